// Round 14
// baseline (249.117 us; speedup 1.0000x reference)
//
#include <hip/hip_runtime.h>

#define K_CODES 1024
#define DIMS    256
#define NROWS   32768   // B*H*W = 32*32*32

// ---------------- main-path geometry ----------------
#define NGROUPS       4      // code groups of 256 (4 codes per lane)
#define ROWS_PER_WAVE 8      // 4096 slices x 4 groups = 16384 waves, 4096 blocks
#define RP            8      // rows per (single) pass

// ws layout (float units)
#define WS_ET    0
#define WS_ESQ   (WS_ET  + DIMS * K_CODES)        // 262144 (et4: 64 x 1024 float4)
#define WS_XSQ   (WS_ESQ + K_CODES)               // +1024
#define WS_CAND  (WS_XSQ + NROWS)                 // +32768
#define WS_NEED_FLOATS (WS_CAND + NGROUPS * NROWS * 2)
#define WS_NEED_BYTES  ((size_t)WS_NEED_FLOATS * 4)

// ---------------------------------------------------------------------------
// numpy-bitwise sum of squares of a 256-element row (verified round 2).
// ---------------------------------------------------------------------------
__device__ __forceinline__ float sq_at(const float* p, int d, int stride) {
#pragma clang fp contract(off)
    const float v = p[(size_t)d * stride];
    return v * v;
}

__device__ __forceinline__ float np_block_sq(const float* p, int stride, int o, int n) {
#pragma clang fp contract(off)
    float r[8];
    #pragma unroll
    for (int k = 0; k < 8; ++k) r[k] = sq_at(p, o + k, stride);
    const int n8 = n - (n % 8);
    for (int i = 8; i < n8; i += 8) {
        #pragma unroll
        for (int k = 0; k < 8; ++k) r[k] = r[k] + sq_at(p, o + i + k, stride);
    }
    float res = ((r[0] + r[1]) + (r[2] + r[3])) + ((r[4] + r[5]) + (r[6] + r[7]));
    for (int i = n8; i < n; ++i) res = res + sq_at(p, o + i, stride);
    return res;
}

__device__ __forceinline__ float np_sumsq_row(const float* p, int stride) {
#pragma clang fp contract(off)
    const float p120 = np_block_sq(p, stride, 1,   120);
    const float p64  = np_block_sq(p, stride, 121, 64);
    const float p71  = np_block_sq(p, stride, 185, 71);
    const float s135 = p64 + p71;
    const float s255 = p120 + s135;
    return sq_at(p, 0, stride) + s255;
}

// ---------------- merged prologue: xsq (128 blk) + esq (4 blk) + tr4 (256 blk)
__global__ void vq_prologue_kernel(const float* __restrict__ x, const float* __restrict__ cb,
                                   float* __restrict__ xsq, float* __restrict__ esq,
                                   float4* __restrict__ et4) {
    const int bid = blockIdx.x;
    if (bid < 128) {                                   // xsq: 32768 rows
        const int n = bid * 256 + threadIdx.x;
        const float* p = x + ((size_t)(n >> 10)) * (DIMS * 1024) + (n & 1023);
        xsq[n] = np_sumsq_row(p, 1024);
    } else if (bid < 132) {                            // esq: 1024 codes
        const int c = (bid - 128) * 256 + threadIdx.x;
        esq[c] = np_sumsq_row(cb + (size_t)c * DIMS, 1);
    } else {                                           // et4[dk][c] panel transpose
        const int idx = (bid - 132) * 256 + threadIdx.x;   // 65536 = 64 dk x 1024 c
        const int dk  = idx & 63;
        const int c   = idx >> 6;
        const float4 v = *reinterpret_cast<const float4*>(cb + (size_t)c * DIMS + dk * 4);
        et4[(size_t)dk * K_CODES + c] = v;
    }
}

// ---------------- main v8: v7 + explicit e ping-pong -------------------------
// R12 post-mortem: single-buffered e = WAR on the e regs -> ~250cy L2 latency
// exposed against only 256cy of FMA per dk (per-wave duty ~50%, busy 78%).
// Ping-pong (load e(dk+1) into the alternate buffer while dk's FMAs run)
// hides it in-wave. Issue stream is already near the measured practical fp32
// rate (m07: 103 TF -> 167us for 17.2 GFLOP; we measure 160-168us issue).
// All e-buffer indices are compile-time constants (full unroll) -> registers.
// FMA chain per (row,code): one accumulator, strictly ascending d (dk asc,
// dd asc) -> bitwise identical to the np/BLAS reference order.

__device__ __forceinline__ void load_e4(const float4* __restrict__ et4, int dk, int c0,
                                        float4 (&e)[4]) {
    const float4* p_ = et4 + (size_t)dk * K_CODES;
    e[0] = p_[c0];
    e[1] = p_[c0 + 64];
    e[2] = p_[c0 + 128];
    e[3] = p_[c0 + 192];
}

__device__ __forceinline__ void compute4(const float* __restrict__ xb, int dk,
                                         const float4 (&e)[4],
                                         float (&acc0)[RP], float (&acc1)[RP],
                                         float (&acc2)[RP], float (&acc3)[RP]) {
    #pragma unroll
    for (int dd = 0; dd < 4; ++dd) {
        float xv[RP];
        #pragma unroll
        for (int r = 0; r < RP; ++r)
            xv[r] = xb[(size_t)(dk * 4 + dd) * 1024 + r];
        const float ev0 = (dd == 0) ? e[0].x : (dd == 1) ? e[0].y : (dd == 2) ? e[0].z : e[0].w;
        const float ev1 = (dd == 0) ? e[1].x : (dd == 1) ? e[1].y : (dd == 2) ? e[1].z : e[1].w;
        const float ev2 = (dd == 0) ? e[2].x : (dd == 1) ? e[2].y : (dd == 2) ? e[2].z : e[2].w;
        const float ev3 = (dd == 0) ? e[3].x : (dd == 1) ? e[3].y : (dd == 2) ? e[3].z : e[3].w;
        #pragma unroll
        for (int r = 0; r < RP; ++r) acc0[r] = fmaf(xv[r], ev0, acc0[r]);
        #pragma unroll
        for (int r = 0; r < RP; ++r) acc1[r] = fmaf(xv[r], ev1, acc1[r]);
        #pragma unroll
        for (int r = 0; r < RP; ++r) acc2[r] = fmaf(xv[r], ev2, acc2[r]);
        #pragma unroll
        for (int r = 0; r < RP; ++r) acc3[r] = fmaf(xv[r], ev3, acc3[r]);
    }
}

__global__ __launch_bounds__(256, 2)
void vq_main8_kernel(const float* __restrict__ x, const float4* __restrict__ et4,
                     const float* __restrict__ esq, const float* __restrict__ xsq,
                     float2* __restrict__ cand) {
    const int wid  = __builtin_amdgcn_readfirstlane((int)(threadIdx.x >> 6));
    const int lane = threadIdx.x & 63;
    const int W     = blockIdx.x * 4 + wid;        // 0..16383
    const int g     = W & (NGROUPS - 1);           // code group of 256
    const int slice = W >> 2;                      // 0..4095 row slice
    const int c0    = g * 256 + lane;              // lane codes: c0 + 64*j, j=0..3
    const int row_base = slice * ROWS_PER_WAVE;    // 8 | 1024 -> one image
    const int b    = row_base >> 10;
    const int hw0  = row_base & 1023;
    const float* xb = x + (size_t)b * (DIMS * 1024) + hw0;   // + d*1024 + r

    const float esq0 = esq[c0];
    const float esq1 = esq[c0 + 64];
    const float esq2 = esq[c0 + 128];
    const float esq3 = esq[c0 + 192];

    float acc0[RP], acc1[RP], acc2[RP], acc3[RP];
    #pragma unroll
    for (int r = 0; r < RP; ++r) { acc0[r] = 0.0f; acc1[r] = 0.0f; acc2[r] = 0.0f; acc3[r] = 0.0f; }

    // e ping-pong: 4 codes x 4 dims per buffer; constant-indexed -> registers
    float4 eA[4], eB[4];

    load_e4(et4, 0, c0, eA);
    for (int dk = 0; dk < DIMS / 4; dk += 2) {
        load_e4(et4, dk + 1, c0, eB);           // prefetch while A computes
        compute4(xb, dk, eA, acc0, acc1, acc2, acc3);
        if (dk + 2 < DIMS / 4) load_e4(et4, dk + 2, c0, eA);
        compute4(xb, dk + 1, eB, acc0, acc1, acc2, acc3);
    }

    // epilogue: d2 = fl(fl(x_sq - 2*dot) + e_sq), exact np op order;
    // in-lane combine ascending c (strict < -> lower code wins ties),
    // then exact first-index 64-lane lexmin butterfly.
    {
#pragma clang fp contract(off)
        float keepv = 0.0f; int keepc = 0;
        #pragma unroll
        for (int r = 0; r < RP; ++r) {
            const float xs_r = xsq[row_base + r];            // uniform
            const float v0 = (xs_r - 2.0f * acc0[r]) + esq0;
            const float v1 = (xs_r - 2.0f * acc1[r]) + esq1;
            const float v2 = (xs_r - 2.0f * acc2[r]) + esq2;
            const float v3 = (xs_r - 2.0f * acc3[r]) + esq3;
            float bv = v0; int bc = c0;
            if (v1 < bv) { bv = v1; bc = c0 + 64; }
            if (v2 < bv) { bv = v2; bc = c0 + 128; }
            if (v3 < bv) { bv = v3; bc = c0 + 192; }
            #pragma unroll
            for (int off = 1; off < 64; off <<= 1) {
                const float ov = __shfl_xor(bv, off, 64);
                const int   oc = __shfl_xor(bc, off, 64);
                if (ov < bv || (ov == bv && oc < bc)) { bv = ov; bc = oc; }
            }
            if (lane == r) { keepv = bv; keepc = bc; }       // lane r keeps row r
        }
        if (lane < RP) {
            cand[(size_t)g * NROWS + row_base + lane] =
                make_float2(keepv, __int_as_float(keepc));
        }
    }
}

// ---------------- cross-group lexmin reduce (groups ascending in code) ------
__global__ void vq_reduce_kernel(const float2* __restrict__ cand, int* __restrict__ out) {
    const int row = blockIdx.x * 256 + threadIdx.x;
    float2 p = cand[row];
    float bv = p.x; int bc = __float_as_int(p.y);
    #pragma unroll
    for (int gg = 1; gg < NGROUPS; ++gg) {
        const float2 q = cand[(size_t)gg * NROWS + row];
        const float v = q.x; const int qc = __float_as_int(q.y);
        if (v < bv || (v == bv && qc < bc)) { bv = v; bc = qc; }
    }
    out[row] = bc;
}

// ===========================================================================
// Fallback path (round-2 kernel, verified passing) — used if ws too small.
// ===========================================================================
#define BM      64
#define BN      128
#define DK      32
#define PITCH   36

__global__ void vq_xsq_kernel(const float* __restrict__ x, float* __restrict__ xsq) {
    const int n = blockIdx.x * 256 + threadIdx.x;
    const float* p = x + ((size_t)(n >> 10)) * (DIMS * 1024) + (n & 1023);
    xsq[n] = np_sumsq_row(p, 1024);
}

__global__ void vq_esq_kernel(const float* __restrict__ cb, float* __restrict__ esq) {
    const int c = blockIdx.x * 256 + threadIdx.x;
    esq[c] = np_sumsq_row(cb + (size_t)c * DIMS, 1);
}

__global__ __launch_bounds__(256, 2)
void vq_main_kernel(const float* __restrict__ x, const float* __restrict__ cb,
                    const float* __restrict__ esq, const float* __restrict__ xsq,
                    int* __restrict__ out) {
    __shared__ float xs[BM * PITCH];

    const int t   = threadIdx.x;
    const int tc  = t & 15;
    const int tr  = t >> 4;
    const int row0 = blockIdx.x * BM;
    const int b   = row0 >> 10;
    const int hw0 = row0 & 1023;
    const float* xb = x + (size_t)b * DIMS * 1024 + hw0;

    float xsqr[4];
    #pragma unroll
    for (int i = 0; i < 4; ++i) xsqr[i] = xsq[row0 + tr * 4 + i];

    float bestv[4];
    int   bestc[4];
    #pragma unroll
    for (int i = 0; i < 4; ++i) { bestv[i] = 3.4e38f; bestc[i] = 0; }

    for (int cc = 0; cc < K_CODES / BN; ++cc) {
        const float* ep[8];
        #pragma unroll
        for (int j = 0; j < 8; ++j)
            ep[j] = cb + (size_t)(cc * BN + tc + 16 * j) * DIMS;

        float acc[4][8];
        #pragma unroll
        for (int i = 0; i < 4; ++i)
            #pragma unroll
            for (int j = 0; j < 8; ++j) acc[i][j] = 0.0f;

        for (int dk = 0; dk < DIMS / DK; ++dk) {
            __syncthreads();
            #pragma unroll
            for (int ii = 0; ii < 2; ++ii) {
                const int li = t + 256 * ii;
                const int d  = (li >> 2) & 31;
                const int h4 = (li & 3) | ((li >> 7) << 2);
                const float4 v = *reinterpret_cast<const float4*>(
                    xb + (size_t)(dk * DK + d) * 1024 + h4 * 4);
                xs[(h4 * 4 + 0) * PITCH + d] = v.x;
                xs[(h4 * 4 + 1) * PITCH + d] = v.y;
                xs[(h4 * 4 + 2) * PITCH + d] = v.z;
                xs[(h4 * 4 + 3) * PITCH + d] = v.w;
            }
            __syncthreads();

            #pragma unroll
            for (int d4 = 0; d4 < DK; d4 += 4) {
                float4 xv[4];
                #pragma unroll
                for (int i = 0; i < 4; ++i)
                    xv[i] = *reinterpret_cast<const float4*>(&xs[(tr * 4 + i) * PITCH + d4]);
                float4 ev[8];
                #pragma unroll
                for (int j = 0; j < 8; ++j)
                    ev[j] = *reinterpret_cast<const float4*>(ep[j] + dk * DK + d4);
                #pragma unroll
                for (int i = 0; i < 4; ++i) {
                    #pragma unroll
                    for (int j = 0; j < 8; ++j) {
                        acc[i][j] = fmaf(xv[i].x, ev[j].x, acc[i][j]);
                        acc[i][j] = fmaf(xv[i].y, ev[j].y, acc[i][j]);
                        acc[i][j] = fmaf(xv[i].z, ev[j].z, acc[i][j]);
                        acc[i][j] = fmaf(xv[i].w, ev[j].w, acc[i][j]);
                    }
                }
            }
        }

        {
#pragma clang fp contract(off)
            #pragma unroll
            for (int j = 0; j < 8; ++j) {
                const int c = cc * BN + tc + 16 * j;
                const float es = esq[c];
                #pragma unroll
                for (int i = 0; i < 4; ++i) {
                    const float t3 = xsqr[i] - 2.0f * acc[i][j];
                    const float v  = t3 + es;
                    if (v < bestv[i]) { bestv[i] = v; bestc[i] = c; }
                }
            }
        }
    }

    __syncthreads();
    float* rv = xs;
    int*   rc = reinterpret_cast<int*>(xs + BM * 16);
    #pragma unroll
    for (int i = 0; i < 4; ++i) {
        const int r = tr * 4 + i;
        rv[r * 16 + tc] = bestv[i];
        rc[r * 16 + tc] = bestc[i];
    }
    __syncthreads();
    if (t < BM) {
        float bv = rv[t * 16];
        int   bc = rc[t * 16];
        #pragma unroll
        for (int k = 1; k < 16; ++k) {
            const float v = rv[t * 16 + k];
            const int   cidx = rc[t * 16 + k];
            if (v < bv || (v == bv && cidx < bc)) { bv = v; bc = cidx; }
        }
        out[row0 + t] = bc;
    }
}

// ===========================================================================
extern "C" void kernel_launch(void* const* d_in, const int* in_sizes, int n_in,
                              void* d_out, int out_size, void* d_ws, size_t ws_size,
                              hipStream_t stream) {
    const float* x  = (const float*)d_in[0];   // [32, 256, 32, 32]
    const float* cb = (const float*)d_in[1];   // [1024, 256]
    int* out = (int*)d_out;                    // [32768] int32
    float* ws = (float*)d_ws;

    if (ws_size >= WS_NEED_BYTES) {
        float4* et4  = (float4*)(ws + WS_ET);
        float*  esq  = ws + WS_ESQ;
        float*  xsq  = ws + WS_XSQ;
        float2* cand = (float2*)(ws + WS_CAND);

        vq_prologue_kernel<<<128 + 4 + 256, 256, 0, stream>>>(x, cb, xsq, esq, et4);
        vq_main8_kernel<<<(NROWS / ROWS_PER_WAVE) * NGROUPS / 4, 256, 0, stream>>>(
            x, et4, esq, xsq, cand);
        vq_reduce_kernel<<<NROWS / 256, 256, 0, stream>>>(cand, out);
    } else {
        float* esq = ws;
        float* xsq = ws + K_CODES;
        vq_xsq_kernel<<<NROWS / 256, 256, 0, stream>>>(x, xsq);
        vq_esq_kernel<<<K_CODES / 256, 256, 0, stream>>>(cb, esq);
        vq_main_kernel<<<NROWS / BM, 256, 0, stream>>>(x, cb, esq, xsq, out);
    }
}

// Round 15
// 236.818 us; speedup vs baseline: 1.0519x; 1.0519x over previous
//
#include <hip/hip_runtime.h>

#define K_CODES 1024
#define DIMS    256
#define NROWS   32768   // B*H*W = 32*32*32

#if defined(__has_builtin)
#if __has_builtin(__builtin_amdgcn_sdot4)
#define HAVE_SDOT4 1
#endif
#endif
#ifndef HAVE_SDOT4
#define HAVE_SDOT4 0
#endif

// ---------------- int8-filter geometry & scales ----------------
#define FGROUPS 4        // code groups of 256 (4 codes per lane)
#define FRP     4        // rows per wave -> 32768 waves, 8192 blocks
#define SX      21.1666666f   // 127/6: x in ±6 sigma, no clipping in practice
#define SE      130048.0f     // 127*1024: e in (-1/1024, 1/1024) exactly in range

// ws layout for int8 path (float/int32 units)
#define WS_XQH  0                              // 64*32768 int
#define WS_XQL  (WS_XQH + 64 * NROWS)          // 64*32768 int
#define WS_EQ   (WS_XQL + 64 * NROWS)          // 64*1024 int
#define WS_ESQ  (WS_EQ  + 64 * K_CODES)
#define WS_XSQ  (WS_ESQ + K_CODES)
#define WS_CAND (WS_XSQ + NROWS)               // float4[FGROUPS*NROWS]
#define WS_INT8_NEED_FLOATS (WS_CAND + FGROUPS * NROWS * 4)
#define WS_INT8_NEED_BYTES  ((size_t)WS_INT8_NEED_FLOATS * 4)

// ws layout for fp32 fallback path (R12, verified 236us)
#define F32_ET    0
#define F32_ESQ   (F32_ET  + DIMS * K_CODES)
#define F32_XSQ   (F32_ESQ + K_CODES)
#define F32_CAND  (F32_XSQ + NROWS)
#define F32_NEED_FLOATS (F32_CAND + 4 * NROWS * 2)
#define F32_NEED_BYTES  ((size_t)F32_NEED_FLOATS * 4)

// ---------------------------------------------------------------------------
// numpy-bitwise sum of squares of a 256-element row (verified round 2).
// ---------------------------------------------------------------------------
__device__ __forceinline__ float sq_at(const float* p, int d, int stride) {
#pragma clang fp contract(off)
    const float v = p[(size_t)d * stride];
    return v * v;
}

__device__ __forceinline__ float np_block_sq(const float* p, int stride, int o, int n) {
#pragma clang fp contract(off)
    float r[8];
    #pragma unroll
    for (int k = 0; k < 8; ++k) r[k] = sq_at(p, o + k, stride);
    const int n8 = n - (n % 8);
    for (int i = 8; i < n8; i += 8) {
        #pragma unroll
        for (int k = 0; k < 8; ++k) r[k] = r[k] + sq_at(p, o + i + k, stride);
    }
    float res = ((r[0] + r[1]) + (r[2] + r[3])) + ((r[4] + r[5]) + (r[6] + r[7]));
    for (int i = n8; i < n; ++i) res = res + sq_at(p, o + i, stride);
    return res;
}

__device__ __forceinline__ float np_sumsq_row(const float* p, int stride) {
#pragma clang fp contract(off)
    const float p120 = np_block_sq(p, stride, 1,   120);
    const float p64  = np_block_sq(p, stride, 121, 64);
    const float p71  = np_block_sq(p, stride, 185, 71);
    const float s135 = p64 + p71;
    const float s255 = p120 + s135;
    return sq_at(p, 0, stride) + s255;
}

// ---------------- quantization helpers --------------------------------------
__device__ __forceinline__ int clamp127(int v) {
    return v < -127 ? -127 : (v > 127 ? 127 : v);
}

__device__ __forceinline__ void quant2(float x, int& qh, int& ql) {
    const float t = x * SX;
    int h = (int)rintf(t);
    h = clamp127(h);
    const float r = t - (float)h;        // |r| <= 0.5 (unclipped case)
    int l = (int)rintf(r * 128.0f);
    l = clamp127(l);
    qh = h; ql = l;
}

__device__ __forceinline__ int pack4(int a, int b, int c, int d) {
    return (a & 255) | ((b & 255) << 8) | ((c & 255) << 16) | ((d & 255) << 24);
}

#if HAVE_SDOT4
// ---------------- int8-path merged prologue ---------------------------------
// blocks: [0,128) xsq | [128,132) esq | [132,260) x-pack | [260,264) e-pack
__global__ void vq_prologue_i8(const float* __restrict__ x, const float* __restrict__ cb,
                               float* __restrict__ xsq, float* __restrict__ esq,
                               int* __restrict__ xqh, int* __restrict__ xql,
                               int* __restrict__ eq) {
    const int bid = blockIdx.x;
    if (bid < 128) {                                   // xsq (np-exact)
        const int n = bid * 256 + threadIdx.x;
        const float* p = x + ((size_t)(n >> 10)) * (DIMS * 1024) + (n & 1023);
        xsq[n] = np_sumsq_row(p, 1024);
    } else if (bid < 132) {                            // esq (np-exact)
        const int c = (bid - 128) * 256 + threadIdx.x;
        esq[c] = np_sumsq_row(cb + (size_t)c * DIMS, 1);
    } else if (bid < 260) {                            // x two-level int8 pack
        const int n = (bid - 132) * 256 + threadIdx.x;
        const float* p = x + ((size_t)(n >> 10)) * (DIMS * 1024) + (n & 1023);
        for (int dk = 0; dk < 64; ++dk) {
            int qh[4], ql[4];
            #pragma unroll
            for (int j = 0; j < 4; ++j)
                quant2(p[(size_t)(dk * 4 + j) * 1024], qh[j], ql[j]);
            xqh[dk * NROWS + n] = pack4(qh[0], qh[1], qh[2], qh[3]);
            xql[dk * NROWS + n] = pack4(ql[0], ql[1], ql[2], ql[3]);
        }
    } else {                                           // e single-level int8 pack
        const int c = (bid - 260) * 256 + threadIdx.x;
        const float* p = cb + (size_t)c * DIMS;
        for (int dk = 0; dk < 64; ++dk) {
            int q[4];
            #pragma unroll
            for (int j = 0; j < 4; ++j) {
                int v = (int)rintf(p[dk * 4 + j] * SE);
                q[j] = clamp127(v);
            }
            eq[dk * K_CODES + c] = pack4(q[0], q[1], q[2], q[3]);
        }
    }
}

// ---------------- int8 filter: approx distances + top-2 per (row, group) ----
// Proven v7 skeleton (lane=code, wave-uniform x via s_load, ping-pong e).
// Per dk: 4 e-dwords + 2x4 uniform x-dwords feed 32 sdot4 (8 MACs each).
// Integer accs are EXACT; only quantization error (sigma_v ~ 2e-6) vs true v.
__device__ __forceinline__ void load_eq4(const int* __restrict__ eq, int dk, int c0,
                                         int (&e)[4]) {
    const int* p_ = eq + (size_t)dk * K_CODES;
    e[0] = p_[c0];
    e[1] = p_[c0 + 64];
    e[2] = p_[c0 + 128];
    e[3] = p_[c0 + 192];
}

__device__ __forceinline__ void dot4_step(const int* __restrict__ xqh,
                                          const int* __restrict__ xql,
                                          int dk, int row_base, const int (&e)[4],
                                          int (&ah)[4][FRP], int (&al)[4][FRP]) {
    int xh[FRP], xl[FRP];
    #pragma unroll
    for (int r = 0; r < FRP; ++r) xh[r] = xqh[(size_t)dk * NROWS + row_base + r]; // uniform
    #pragma unroll
    for (int r = 0; r < FRP; ++r) xl[r] = xql[(size_t)dk * NROWS + row_base + r]; // uniform
    #pragma unroll
    for (int j = 0; j < 4; ++j) {
        #pragma unroll
        for (int r = 0; r < FRP; ++r) {
            ah[j][r] = __builtin_amdgcn_sdot4(e[j], xh[r], ah[j][r], false);
            al[j][r] = __builtin_amdgcn_sdot4(e[j], xl[r], al[j][r], false);
        }
    }
}

__global__ __launch_bounds__(256, 2)
void vq_filter_kernel(const int* __restrict__ xqh, const int* __restrict__ xql,
                      const int* __restrict__ eq, const float* __restrict__ esq,
                      float4* __restrict__ cand) {
    const int wid  = __builtin_amdgcn_readfirstlane((int)(threadIdx.x >> 6));
    const int lane = threadIdx.x & 63;
    const int W     = blockIdx.x * 4 + wid;        // 0..32767
    const int g     = W & (FGROUPS - 1);           // code group of 256
    const int slice = W >> 2;                      // 0..8191
    const int c0    = g * 256 + lane;              // lane codes: c0 + 64*j
    const int row_base = slice * FRP;

    float esqv[4];
    #pragma unroll
    for (int j = 0; j < 4; ++j) esqv[j] = esq[c0 + 64 * j];

    int ah[4][FRP], al[4][FRP];
    #pragma unroll
    for (int j = 0; j < 4; ++j)
        #pragma unroll
        for (int r = 0; r < FRP; ++r) { ah[j][r] = 0; al[j][r] = 0; }

    int eA[4], eB[4];
    load_eq4(eq, 0, c0, eA);
    for (int dk = 0; dk < 64; dk += 2) {
        load_eq4(eq, dk + 1, c0, eB);
        dot4_step(xqh, xql, dk, row_base, eA, ah, al);
        if (dk + 2 < 64) load_eq4(eq, dk + 2, c0, eA);
        dot4_step(xqh, xql, dk + 1, row_base, eB, ah, al);
    }

    // epilogue: approx va, then per-row top-2 over the group's 256 codes
    // (in-lane top-2 of 4 codes, then two 64-lane lexmin butterfly extractions)
    float s0v = 0.0f, s1v = 0.0f; int s0c = 0, s1c = 0;
    #pragma unroll
    for (int r = 0; r < FRP; ++r) {
        float l0v = 3.4e38f, l1v = 3.4e38f; int l0c = 0, l1c = 0;
        #pragma unroll
        for (int j = 0; j < 4; ++j) {
            const float dot = ((float)ah[j][r] + (float)al[j][r] * 0.0078125f)
                              * (1.0f / (SX * SE));
            const float va = fmaf(-2.0f, dot, esqv[j]);
            const int   c  = c0 + 64 * j;
            if (va < l0v)      { l1v = l0v; l1c = l0c; l0v = va; l0c = c; }
            else if (va < l1v) { l1v = va; l1c = c; }
        }
        // extraction 1: global lexmin over lanes
        float m1v = l0v; int m1c = l0c;
        #pragma unroll
        for (int off = 1; off < 64; off <<= 1) {
            const float ov = __shfl_xor(m1v, off, 64);
            const int   oc = __shfl_xor(m1c, off, 64);
            if (ov < m1v || (ov == m1v && oc < m1c)) { m1v = ov; m1c = oc; }
        }
        // pop winner in its owner lane
        if (l0c == m1c) { l0v = l1v; l0c = l1c; }
        // extraction 2
        float m2v = l0v; int m2c = l0c;
        #pragma unroll
        for (int off = 1; off < 64; off <<= 1) {
            const float ov = __shfl_xor(m2v, off, 64);
            const int   oc = __shfl_xor(m2c, off, 64);
            if (ov < m2v || (ov == m2v && oc < m2c)) { m2v = ov; m2c = oc; }
        }
        if (lane == r) { s0v = m1v; s0c = m1c; s1v = m2v; s1c = m2c; }
    }
    if (lane < FRP) {
        cand[(size_t)g * NROWS + row_base + lane] =
            make_float4(s0v, __int_as_float(s0c), s1v, __int_as_float(s1c));
    }
}

// ---------------- exact refine: np-order fp32 over 8 candidates/row ---------
__global__ __launch_bounds__(256, 2)
void vq_refine_kernel(const float* __restrict__ x, const float* __restrict__ cb,
                      const float* __restrict__ esq, const float* __restrict__ xsq,
                      const float4* __restrict__ cand, int* __restrict__ out) {
    const int n  = blockIdx.x * 256 + threadIdx.x;
    const int b  = n >> 10;
    const int hw = n & 1023;
    const float* xr = x + (size_t)b * (DIMS * 1024) + hw;   // + d*1024

    int cc[8];
    #pragma unroll
    for (int g = 0; g < FGROUPS; ++g) {
        const float4 q = cand[(size_t)g * NROWS + n];
        cc[2 * g]     = __float_as_int(q.y);
        cc[2 * g + 1] = __float_as_int(q.w);
    }

    float acc[8];
    #pragma unroll
    for (int k = 0; k < 8; ++k) acc[k] = 0.0f;

    // exact dot: sequential fma, strictly ascending d (BLAS/np order),
    // one accumulator per candidate; x chunk-preloaded (shared by candidates).
    for (int d0 = 0; d0 < DIMS; d0 += 32) {
        float xv[32];
        #pragma unroll
        for (int i = 0; i < 32; ++i) xv[i] = xr[(size_t)(d0 + i) * 1024];
        #pragma unroll
        for (int k = 0; k < 8; ++k) {
            const float* ec = cb + (size_t)cc[k] * DIMS + d0;
            #pragma unroll
            for (int i = 0; i < 32; ++i) acc[k] = fmaf(xv[i], ec[i], acc[k]);
        }
    }

    {
#pragma clang fp contract(off)
        const float xs_n = xsq[n];
        float bestv = 3.4e38f; int bestc = 0x7fffffff;
        #pragma unroll
        for (int k = 0; k < 8; ++k) {
            const float t3 = xs_n - 2.0f * acc[k];
            const float v  = t3 + esq[cc[k]];
            if (v < bestv || (v == bestv && cc[k] < bestc)) { bestv = v; bestc = cc[k]; }
        }
        out[n] = bestc;
    }
}
#endif  // HAVE_SDOT4

// ===========================================================================
// fp32 fallback path — R12 verified (prologue + v7 main + reduce, 236us).
// ===========================================================================
__global__ void vq_prologue_f32(const float* __restrict__ x, const float* __restrict__ cb,
                                float* __restrict__ xsq, float* __restrict__ esq,
                                float4* __restrict__ et4) {
    const int bid = blockIdx.x;
    if (bid < 128) {
        const int n = bid * 256 + threadIdx.x;
        const float* p = x + ((size_t)(n >> 10)) * (DIMS * 1024) + (n & 1023);
        xsq[n] = np_sumsq_row(p, 1024);
    } else if (bid < 132) {
        const int c = (bid - 128) * 256 + threadIdx.x;
        esq[c] = np_sumsq_row(cb + (size_t)c * DIMS, 1);
    } else {
        const int idx = (bid - 132) * 256 + threadIdx.x;
        const int dk  = idx & 63;
        const int c   = idx >> 6;
        const float4 v = *reinterpret_cast<const float4*>(cb + (size_t)c * DIMS + dk * 4);
        et4[(size_t)dk * K_CODES + c] = v;
    }
}

__global__ __launch_bounds__(256, 2)
void vq_main7_kernel(const float* __restrict__ x, const float4* __restrict__ et4,
                     const float* __restrict__ esq, const float* __restrict__ xsq,
                     float2* __restrict__ cand) {
    const int wid  = __builtin_amdgcn_readfirstlane((int)(threadIdx.x >> 6));
    const int lane = threadIdx.x & 63;
    const int W     = blockIdx.x * 4 + wid;
    const int g     = W & 3;
    const int slice = W >> 2;
    const int c0    = g * 256 + lane;
    const int row_base = slice * 8;
    const int b    = row_base >> 10;
    const int hw0  = row_base & 1023;
    const float* xb = x + (size_t)b * (DIMS * 1024) + hw0;

    const float esq0 = esq[c0];
    const float esq1 = esq[c0 + 64];
    const float esq2 = esq[c0 + 128];
    const float esq3 = esq[c0 + 192];

    float acc0[8], acc1[8], acc2[8], acc3[8];
    #pragma unroll
    for (int r = 0; r < 8; ++r) { acc0[r] = 0.0f; acc1[r] = 0.0f; acc2[r] = 0.0f; acc3[r] = 0.0f; }

    for (int dk = 0; dk < DIMS / 4; ++dk) {
        const float4* ep = et4 + (size_t)dk * K_CODES;
        const float4 e0 = ep[c0];
        const float4 e1 = ep[c0 + 64];
        const float4 e2 = ep[c0 + 128];
        const float4 e3 = ep[c0 + 192];

        #pragma unroll
        for (int dd = 0; dd < 4; ++dd) {
            float xv[8];
            #pragma unroll
            for (int r = 0; r < 8; ++r)
                xv[r] = xb[(size_t)(dk * 4 + dd) * 1024 + r];
            const float ev0 = (dd == 0) ? e0.x : (dd == 1) ? e0.y : (dd == 2) ? e0.z : e0.w;
            const float ev1 = (dd == 0) ? e1.x : (dd == 1) ? e1.y : (dd == 2) ? e1.z : e1.w;
            const float ev2 = (dd == 0) ? e2.x : (dd == 1) ? e2.y : (dd == 2) ? e2.z : e2.w;
            const float ev3 = (dd == 0) ? e3.x : (dd == 1) ? e3.y : (dd == 2) ? e3.z : e3.w;
            #pragma unroll
            for (int r = 0; r < 8; ++r) acc0[r] = fmaf(xv[r], ev0, acc0[r]);
            #pragma unroll
            for (int r = 0; r < 8; ++r) acc1[r] = fmaf(xv[r], ev1, acc1[r]);
            #pragma unroll
            for (int r = 0; r < 8; ++r) acc2[r] = fmaf(xv[r], ev2, acc2[r]);
            #pragma unroll
            for (int r = 0; r < 8; ++r) acc3[r] = fmaf(xv[r], ev3, acc3[r]);
        }
    }

    {
#pragma clang fp contract(off)
        float keepv = 0.0f; int keepc = 0;
        #pragma unroll
        for (int r = 0; r < 8; ++r) {
            const float xs_r = xsq[row_base + r];
            const float v0 = (xs_r - 2.0f * acc0[r]) + esq0;
            const float v1 = (xs_r - 2.0f * acc1[r]) + esq1;
            const float v2 = (xs_r - 2.0f * acc2[r]) + esq2;
            const float v3 = (xs_r - 2.0f * acc3[r]) + esq3;
            float bv = v0; int bc = c0;
            if (v1 < bv) { bv = v1; bc = c0 + 64; }
            if (v2 < bv) { bv = v2; bc = c0 + 128; }
            if (v3 < bv) { bv = v3; bc = c0 + 192; }
            #pragma unroll
            for (int off = 1; off < 64; off <<= 1) {
                const float ov = __shfl_xor(bv, off, 64);
                const int   oc = __shfl_xor(bc, off, 64);
                if (ov < bv || (ov == bv && oc < bc)) { bv = ov; bc = oc; }
            }
            if (lane == r) { keepv = bv; keepc = bc; }
        }
        if (lane < 8) {
            cand[(size_t)g * NROWS + row_base + lane] =
                make_float2(keepv, __int_as_float(keepc));
        }
    }
}

__global__ void vq_reduce_kernel(const float2* __restrict__ cand, int* __restrict__ out) {
    const int row = blockIdx.x * 256 + threadIdx.x;
    float2 p = cand[row];
    float bv = p.x; int bc = __float_as_int(p.y);
    #pragma unroll
    for (int gg = 1; gg < 4; ++gg) {
        const float2 q = cand[(size_t)gg * NROWS + row];
        const float v = q.x; const int qc = __float_as_int(q.y);
        if (v < bv || (v == bv && qc < bc)) { bv = v; bc = qc; }
    }
    out[row] = bc;
}

// ===========================================================================
extern "C" void kernel_launch(void* const* d_in, const int* in_sizes, int n_in,
                              void* d_out, int out_size, void* d_ws, size_t ws_size,
                              hipStream_t stream) {
    const float* x  = (const float*)d_in[0];   // [32, 256, 32, 32]
    const float* cb = (const float*)d_in[1];   // [1024, 256]
    int* out = (int*)d_out;                    // [32768] int32
    float* ws = (float*)d_ws;

#if HAVE_SDOT4
    if (ws_size >= WS_INT8_NEED_BYTES) {
        int*    xqh  = (int*)(ws + WS_XQH);
        int*    xql  = (int*)(ws + WS_XQL);
        int*    eqp  = (int*)(ws + WS_EQ);
        float*  esq  = ws + WS_ESQ;
        float*  xsq  = ws + WS_XSQ;
        float4* cand = (float4*)(ws + WS_CAND);

        vq_prologue_i8<<<264, 256, 0, stream>>>(x, cb, xsq, esq, xqh, xql, eqp);
        vq_filter_kernel<<<(NROWS / FRP) * FGROUPS / 4, 256, 0, stream>>>(
            xqh, xql, eqp, esq, cand);
        vq_refine_kernel<<<NROWS / 256, 256, 0, stream>>>(x, cb, esq, xsq, cand, out);
        return;
    }
#endif
    // fp32 fallback (R12, verified): needs 5.25MB ws (held since round 3)
    {
        float4* et4  = (float4*)(ws + F32_ET);
        float*  esq  = ws + F32_ESQ;
        float*  xsq  = ws + F32_XSQ;
        float2* cand = (float2*)(ws + F32_CAND);

        vq_prologue_f32<<<128 + 4 + 256, 256, 0, stream>>>(x, cb, xsq, esq, et4);
        vq_main7_kernel<<<(NROWS / 8) * 4 / 4, 256, 0, stream>>>(x, et4, esq, xsq, cand);
        vq_reduce_kernel<<<NROWS / 256, 256, 0, stream>>>(cand, out);
    }
}

// Round 16
// 236.331 us; speedup vs baseline: 1.0541x; 1.0021x over previous
//
#include <hip/hip_runtime.h>

#define K_CODES 1024
#define DIMS    256
#define NROWS   32768   // B*H*W = 32*32*32

typedef __attribute__((ext_vector_type(8))) short bf16x8;
typedef __attribute__((ext_vector_type(4))) float f32x4;

#if defined(__has_builtin)
#if __has_builtin(__builtin_amdgcn_mfma_f32_16x16x32_bf16)
#define HAVE_MFMA_BF16 1
#endif
#endif
#ifndef HAVE_MFMA_BF16
#define HAVE_MFMA_BF16 0
#endif

// ---------------- MFMA-path ws layout (float units), total ~1.7 MB ----------
#define WS_BH    0                             // 262144 ushort = 131072 floats
#define WS_BL    (WS_BH + 131072)
#define WS_ESQ   (WS_BL + 131072)
#define WS_XSQ   (WS_ESQ + K_CODES)
#define WS_CAND  (WS_XSQ + NROWS)              // int4 per row
#define WS_MFMA_NEED_FLOATS (WS_CAND + NROWS * 4)
#define WS_MFMA_NEED_BYTES  ((size_t)WS_MFMA_NEED_FLOATS * 4)

// fp32 fallback layout (R12 verified)
#define F32_ET    0
#define F32_ESQ   (F32_ET  + DIMS * K_CODES)
#define F32_XSQ   (F32_ESQ + K_CODES)
#define F32_CAND  (F32_XSQ + NROWS)
#define F32_NEED_FLOATS (F32_CAND + 4 * NROWS * 2)
#define F32_NEED_BYTES  ((size_t)F32_NEED_FLOATS * 4)

// ---------------------------------------------------------------------------
// numpy-bitwise sum of squares of a 256-element row (verified round 2).
// ---------------------------------------------------------------------------
__device__ __forceinline__ float sq_at(const float* p, int d, int stride) {
#pragma clang fp contract(off)
    const float v = p[(size_t)d * stride];
    return v * v;
}

__device__ __forceinline__ float np_block_sq(const float* p, int stride, int o, int n) {
#pragma clang fp contract(off)
    float r[8];
    #pragma unroll
    for (int k = 0; k < 8; ++k) r[k] = sq_at(p, o + k, stride);
    const int n8 = n - (n % 8);
    for (int i = 8; i < n8; i += 8) {
        #pragma unroll
        for (int k = 0; k < 8; ++k) r[k] = r[k] + sq_at(p, o + i + k, stride);
    }
    float res = ((r[0] + r[1]) + (r[2] + r[3])) + ((r[4] + r[5]) + (r[6] + r[7]));
    for (int i = n8; i < n; ++i) res = res + sq_at(p, o + i, stride);
    return res;
}

__device__ __forceinline__ float np_sumsq_row(const float* p, int stride) {
#pragma clang fp contract(off)
    const float p120 = np_block_sq(p, stride, 1,   120);
    const float p64  = np_block_sq(p, stride, 121, 64);
    const float p71  = np_block_sq(p, stride, 185, 71);
    const float s135 = p64 + p71;
    const float s255 = p120 + s135;
    return sq_at(p, 0, stride) + s255;
}

// bf16 round-to-nearest-even (same helper used for A and B packs: consistency)
__device__ __forceinline__ unsigned short f32_to_bf16_rne(float f) {
    unsigned u = __float_as_uint(f);
    u += 0x7fffu + ((u >> 16) & 1u);
    return (unsigned short)(u >> 16);
}

#if HAVE_MFMA_BF16
// ---------------- prologue: xsq(128) | esq(4) | B-pack(1024 blocks) ---------
// B-pack layout [kc][t][lane][i] (slot->k map: k = kc*32 + (lane>>4)*8 + i,
// col c = t*16 + (lane&15)). A uses the SAME map -> any consistent bijection
// is correct regardless of the hardware's internal k ordering.
__global__ void vq_prologue_mfma(const float* __restrict__ x, const float* __restrict__ cb,
                                 float* __restrict__ xsq, float* __restrict__ esq,
                                 unsigned short* __restrict__ bh, unsigned short* __restrict__ bl) {
    const int bid = blockIdx.x;
    if (bid < 128) {                                   // xsq (np-exact)
        const int n = bid * 256 + threadIdx.x;
        const float* p = x + ((size_t)(n >> 10)) * (DIMS * 1024) + (n & 1023);
        xsq[n] = np_sumsq_row(p, 1024);
    } else if (bid < 132) {                            // esq (np-exact)
        const int c = (bid - 128) * 256 + threadIdx.x;
        esq[c] = np_sumsq_row(cb + (size_t)c * DIMS, 1);
    } else {                                           // two-level bf16 B pack
        const int idx = (bid - 132) * 256 + threadIdx.x;   // 0..262143
        const int i  = idx & 7;
        const int ln = (idx >> 3) & 63;
        const int t  = (idx >> 9) & 63;
        const int kc = idx >> 15;
        const int c  = t * 16 + (ln & 15);
        const int k  = kc * 32 + (ln >> 4) * 8 + i;
        const float v = cb[(size_t)c * DIMS + k];
        const unsigned short hbits = f32_to_bf16_rne(v);
        const float hv = __uint_as_float((unsigned)hbits << 16);
        bh[idx] = hbits;
        bl[idx] = f32_to_bf16_rne(v - hv);             // residual plane
    }
}

// ---------------- MFMA filter: approx v, top-3 codes per row ----------------
// Wave = 16 rows x all 1024 codes (64 col-tiles). Per tile: 8 kchunks x
// 2 MFMA (eh + el planes, separate acc chains for ILP). Epilogue per tile:
// per-lane top-2 insert (cols == lane&15 mod 16). End: per-row 3-extraction
// lexmin merge over the 16-lane subgroup -> 3 distinct candidate codes.
// C/D mapping (m89-verified): col = lane&15, row = (lane>>4)*4 + j.
__global__ __launch_bounds__(256, 2)
void vq_mfma_filter(const float* __restrict__ x, const unsigned short* __restrict__ bh,
                    const unsigned short* __restrict__ bl, const float* __restrict__ esq,
                    int4* __restrict__ cand) {
    const int wid  = __builtin_amdgcn_readfirstlane((int)(threadIdx.x >> 6));
    const int lane = threadIdx.x & 63;
    const int rowblk = blockIdx.x * 4 + wid;       // 0..2047
    const int row0 = rowblk * 16;                  // 16 | 1024 -> one image
    const int b  = row0 >> 10;
    const int hw = (row0 & 1023) + (lane & 15);
    const float* xb = x + (size_t)b * (DIMS * 1024) + hw;
    const int g = lane >> 4;

    // A fragments: A[m = lane&15][k = kc*32 + g*8 + i], bf16 RNE on the fly
    bf16x8 afr[8];
    #pragma unroll
    for (int kc = 0; kc < 8; ++kc) {
        #pragma unroll
        for (int i = 0; i < 8; ++i) {
            const int k = kc * 32 + g * 8 + i;
            afr[kc][i] = (short)f32_to_bf16_rne(xb[(size_t)k * 1024]);
        }
    }

    float lv[4][2]; int lc[4][2];
    #pragma unroll
    for (int j = 0; j < 4; ++j) {
        lv[j][0] = 3.4e38f; lv[j][1] = 3.4e38f;
        lc[j][0] = 0x7fffffff; lc[j][1] = 0x7fffffff;
    }

    const bf16x8* bhv = reinterpret_cast<const bf16x8*>(bh);
    const bf16x8* blv = reinterpret_cast<const bf16x8*>(bl);

    for (int t = 0; t < 64; ++t) {
        f32x4 acch = {0.f, 0.f, 0.f, 0.f};
        f32x4 accl = {0.f, 0.f, 0.f, 0.f};
        #pragma unroll
        for (int kc = 0; kc < 8; ++kc) {
            const int bidx = (kc * 64 + t) * 64 + lane;    // coalesced dwordx4
            acch = __builtin_amdgcn_mfma_f32_16x16x32_bf16(afr[kc], bhv[bidx], acch, 0, 0, 0);
            accl = __builtin_amdgcn_mfma_f32_16x16x32_bf16(afr[kc], blv[bidx], accl, 0, 0, 0);
        }
        const int   c  = t * 16 + (lane & 15);
        const float es = esq[c];
        #pragma unroll
        for (int j = 0; j < 4; ++j) {
            // x_sq omitted: constant per row, ordering-invariant for the filter
            const float v = fmaf(-2.0f, acch[j] + accl[j], es);
            if (v < lv[j][0]) { lv[j][1] = lv[j][0]; lc[j][1] = lc[j][0]; lv[j][0] = v; lc[j][0] = c; }
            else if (v < lv[j][1]) { lv[j][1] = v; lc[j][1] = c; }
        }
    }

    // per-row merge: 3 lexmin extractions over the 16-lane subgroup
    int c3[4][3];
    #pragma unroll
    for (int j = 0; j < 4; ++j) {
        float a1v = lv[j][0]; int a1c = lc[j][0];
        float a2v = lv[j][1]; int a2c = lc[j][1];
        #pragma unroll
        for (int e = 0; e < 3; ++e) {
            float mv = a1v; int mc = a1c;
            #pragma unroll
            for (int off = 1; off < 16; off <<= 1) {
                const float ov = __shfl_xor(mv, off, 16);
                const int   oc = __shfl_xor(mc, off, 16);
                if (ov < mv || (ov == mv && oc < mc)) { mv = ov; mc = oc; }
            }
            c3[j][e] = mc;
            if (a1c == mc) { a1v = a2v; a1c = a2c; a2v = 3.4e38f; a2c = 0x7fffffff; }  // pop owner
        }
    }
    if ((lane & 15) == 0) {
        #pragma unroll
        for (int j = 0; j < 4; ++j)
            cand[row0 + g * 4 + j] = make_int4(c3[j][0], c3[j][1], c3[j][2], 0);
    }
}

// ---------------- exact refine: np-order fp32 over 3 candidates/row ---------
__global__ __launch_bounds__(256, 2)
void vq_refine3(const float* __restrict__ x, const float* __restrict__ cb,
                const float* __restrict__ esq, const float* __restrict__ xsq,
                const int4* __restrict__ cand, int* __restrict__ out) {
    const int n  = blockIdx.x * 256 + threadIdx.x;
    const int b  = n >> 10;
    const int hw = n & 1023;
    const float* xr = x + (size_t)b * (DIMS * 1024) + hw;
    const int4 cd = cand[n];
    const int cc[3] = {cd.x, cd.y, cd.z};

    float acc[3] = {0.f, 0.f, 0.f};
    // exact dot: sequential fma, strictly ascending d (BLAS/np order)
    for (int d0 = 0; d0 < DIMS; d0 += 32) {
        float xv[32];
        #pragma unroll
        for (int i = 0; i < 32; ++i) xv[i] = xr[(size_t)(d0 + i) * 1024];
        #pragma unroll
        for (int k = 0; k < 3; ++k) {
            const float* ec = cb + (size_t)cc[k] * DIMS + d0;
            #pragma unroll
            for (int i = 0; i < 32; ++i) acc[k] = fmaf(xv[i], ec[i], acc[k]);
        }
    }
    {
#pragma clang fp contract(off)
        const float xs_n = xsq[n];
        float bestv = 3.4e38f; int bestc = 0x7fffffff;
        #pragma unroll
        for (int k = 0; k < 3; ++k) {
            const float t3 = xs_n - 2.0f * acc[k];
            const float v  = t3 + esq[cc[k]];
            if (v < bestv || (v == bestv && cc[k] < bestc)) { bestv = v; bestc = cc[k]; }
        }
        out[n] = bestc;
    }
}
#endif  // HAVE_MFMA_BF16

// ===========================================================================
// fp32 fallback path — R12 verified (prologue + v7 main + reduce, 236us).
// ===========================================================================
__global__ void vq_prologue_f32(const float* __restrict__ x, const float* __restrict__ cb,
                                float* __restrict__ xsq, float* __restrict__ esq,
                                float4* __restrict__ et4) {
    const int bid = blockIdx.x;
    if (bid < 128) {
        const int n = bid * 256 + threadIdx.x;
        const float* p = x + ((size_t)(n >> 10)) * (DIMS * 1024) + (n & 1023);
        xsq[n] = np_sumsq_row(p, 1024);
    } else if (bid < 132) {
        const int c = (bid - 128) * 256 + threadIdx.x;
        esq[c] = np_sumsq_row(cb + (size_t)c * DIMS, 1);
    } else {
        const int idx = (bid - 132) * 256 + threadIdx.x;
        const int dk  = idx & 63;
        const int c   = idx >> 6;
        const float4 v = *reinterpret_cast<const float4*>(cb + (size_t)c * DIMS + dk * 4);
        et4[(size_t)dk * K_CODES + c] = v;
    }
}

__global__ __launch_bounds__(256, 2)
void vq_main7_kernel(const float* __restrict__ x, const float4* __restrict__ et4,
                     const float* __restrict__ esq, const float* __restrict__ xsq,
                     float2* __restrict__ cand) {
    const int wid  = __builtin_amdgcn_readfirstlane((int)(threadIdx.x >> 6));
    const int lane = threadIdx.x & 63;
    const int W     = blockIdx.x * 4 + wid;
    const int g     = W & 3;
    const int slice = W >> 2;
    const int c0    = g * 256 + lane;
    const int row_base = slice * 8;
    const int b    = row_base >> 10;
    const int hw0  = row_base & 1023;
    const float* xb = x + (size_t)b * (DIMS * 1024) + hw0;

    const float esq0 = esq[c0];
    const float esq1 = esq[c0 + 64];
    const float esq2 = esq[c0 + 128];
    const float esq3 = esq[c0 + 192];

    float acc0[8], acc1[8], acc2[8], acc3[8];
    #pragma unroll
    for (int r = 0; r < 8; ++r) { acc0[r] = 0.0f; acc1[r] = 0.0f; acc2[r] = 0.0f; acc3[r] = 0.0f; }

    for (int dk = 0; dk < DIMS / 4; ++dk) {
        const float4* ep = et4 + (size_t)dk * K_CODES;
        const float4 e0 = ep[c0];
        const float4 e1 = ep[c0 + 64];
        const float4 e2 = ep[c0 + 128];
        const float4 e3 = ep[c0 + 192];

        #pragma unroll
        for (int dd = 0; dd < 4; ++dd) {
            float xv[8];
            #pragma unroll
            for (int r = 0; r < 8; ++r)
                xv[r] = xb[(size_t)(dk * 4 + dd) * 1024 + r];
            const float ev0 = (dd == 0) ? e0.x : (dd == 1) ? e0.y : (dd == 2) ? e0.z : e0.w;
            const float ev1 = (dd == 0) ? e1.x : (dd == 1) ? e1.y : (dd == 2) ? e1.z : e1.w;
            const float ev2 = (dd == 0) ? e2.x : (dd == 1) ? e2.y : (dd == 2) ? e2.z : e2.w;
            const float ev3 = (dd == 0) ? e3.x : (dd == 1) ? e3.y : (dd == 2) ? e3.z : e3.w;
            #pragma unroll
            for (int r = 0; r < 8; ++r) acc0[r] = fmaf(xv[r], ev0, acc0[r]);
            #pragma unroll
            for (int r = 0; r < 8; ++r) acc1[r] = fmaf(xv[r], ev1, acc1[r]);
            #pragma unroll
            for (int r = 0; r < 8; ++r) acc2[r] = fmaf(xv[r], ev2, acc2[r]);
            #pragma unroll
            for (int r = 0; r < 8; ++r) acc3[r] = fmaf(xv[r], ev3, acc3[r]);
        }
    }

    {
#pragma clang fp contract(off)
        float keepv = 0.0f; int keepc = 0;
        #pragma unroll
        for (int r = 0; r < 8; ++r) {
            const float xs_r = xsq[row_base + r];
            const float v0 = (xs_r - 2.0f * acc0[r]) + esq0;
            const float v1 = (xs_r - 2.0f * acc1[r]) + esq1;
            const float v2 = (xs_r - 2.0f * acc2[r]) + esq2;
            const float v3 = (xs_r - 2.0f * acc3[r]) + esq3;
            float bv = v0; int bc = c0;
            if (v1 < bv) { bv = v1; bc = c0 + 64; }
            if (v2 < bv) { bv = v2; bc = c0 + 128; }
            if (v3 < bv) { bv = v3; bc = c0 + 192; }
            #pragma unroll
            for (int off = 1; off < 64; off <<= 1) {
                const float ov = __shfl_xor(bv, off, 64);
                const int   oc = __shfl_xor(bc, off, 64);
                if (ov < bv || (ov == bv && oc < bc)) { bv = ov; bc = oc; }
            }
            if (lane == r) { keepv = bv; keepc = bc; }
        }
        if (lane < 8) {
            cand[(size_t)g * NROWS + row_base + lane] =
                make_float2(keepv, __int_as_float(keepc));
        }
    }
}

__global__ void vq_reduce_kernel(const float2* __restrict__ cand, int* __restrict__ out) {
    const int row = blockIdx.x * 256 + threadIdx.x;
    float2 p = cand[row];
    float bv = p.x; int bc = __float_as_int(p.y);
    #pragma unroll
    for (int gg = 1; gg < 4; ++gg) {
        const float2 q = cand[(size_t)gg * NROWS + row];
        const float v = q.x; const int qc = __float_as_int(q.y);
        if (v < bv || (v == bv && qc < bc)) { bv = v; bc = qc; }
    }
    out[row] = bc;
}

// ===========================================================================
extern "C" void kernel_launch(void* const* d_in, const int* in_sizes, int n_in,
                              void* d_out, int out_size, void* d_ws, size_t ws_size,
                              hipStream_t stream) {
    const float* x  = (const float*)d_in[0];   // [32, 256, 32, 32]
    const float* cb = (const float*)d_in[1];   // [1024, 256]
    int* out = (int*)d_out;                    // [32768] int32
    float* ws = (float*)d_ws;

#if HAVE_MFMA_BF16
    if (ws_size >= WS_MFMA_NEED_BYTES) {
        unsigned short* bh = (unsigned short*)(ws + WS_BH);
        unsigned short* bl = (unsigned short*)(ws + WS_BL);
        float* esq = ws + WS_ESQ;
        float* xsq = ws + WS_XSQ;
        int4*  cnd = (int4*)(ws + WS_CAND);

        vq_prologue_mfma<<<128 + 4 + 1024, 256, 0, stream>>>(x, cb, xsq, esq, bh, bl);
        vq_mfma_filter<<<512, 256, 0, stream>>>(x, bh, bl, esq, cnd);
        vq_refine3<<<NROWS / 256, 256, 0, stream>>>(x, cb, esq, xsq, cnd, out);
        return;
    }
#endif
    // fp32 fallback (R12, verified 236us)
    {
        float4* et4  = (float4*)(ws + F32_ET);
        float*  esq  = ws + F32_ESQ;
        float*  xsq  = ws + F32_XSQ;
        float2* cand = (float2*)(ws + F32_CAND);

        vq_prologue_f32<<<128 + 4 + 256, 256, 0, stream>>>(x, cb, xsq, esq, et4);
        vq_main7_kernel<<<(NROWS / 8) * 4 / 4, 256, 0, stream>>>(x, et4, esq, xsq, cand);
        vq_reduce_kernel<<<NROWS / 256, 256, 0, stream>>>(cand, out);
    }
}

// Round 17
// 217.492 us; speedup vs baseline: 1.1454x; 1.0866x over previous
//
#include <hip/hip_runtime.h>

#define K_CODES 1024
#define DIMS    256
#define NROWS   32768   // B*H*W = 32*32*32

typedef __attribute__((ext_vector_type(8))) short bf16x8;
typedef __attribute__((ext_vector_type(4))) float f32x4;

// NOTE (R16 lesson): do NOT gate host launch logic on __has_builtin of device
// builtins — the host compile pass reports 0 and silently selects the fallback.
// mfma_f32_16x16x32_bf16 is verified present on gfx950 (guide §3 intrinsic list).

// ---------------- MFMA-path ws layout (float units), total ~1.7 MB ----------
#define WS_BH    0                             // 262144 ushort = 131072 floats
#define WS_BL    (WS_BH + 131072)
#define WS_ESQ   (WS_BL + 131072)
#define WS_XSQ   (WS_ESQ + K_CODES)
#define WS_CAND  (WS_XSQ + NROWS)              // int4 per row
#define WS_MFMA_NEED_FLOATS (WS_CAND + NROWS * 4)
#define WS_MFMA_NEED_BYTES  ((size_t)WS_MFMA_NEED_FLOATS * 4)

// fp32 fallback layout (R12 verified)
#define F32_ET    0
#define F32_ESQ   (F32_ET  + DIMS * K_CODES)
#define F32_XSQ   (F32_ESQ + K_CODES)
#define F32_CAND  (F32_XSQ + NROWS)
#define F32_NEED_FLOATS (F32_CAND + 4 * NROWS * 2)
#define F32_NEED_BYTES  ((size_t)F32_NEED_FLOATS * 4)

// ---------------------------------------------------------------------------
// numpy-bitwise sum of squares of a 256-element row (verified round 2).
// ---------------------------------------------------------------------------
__device__ __forceinline__ float sq_at(const float* p, int d, int stride) {
#pragma clang fp contract(off)
    const float v = p[(size_t)d * stride];
    return v * v;
}

__device__ __forceinline__ float np_block_sq(const float* p, int stride, int o, int n) {
#pragma clang fp contract(off)
    float r[8];
    #pragma unroll
    for (int k = 0; k < 8; ++k) r[k] = sq_at(p, o + k, stride);
    const int n8 = n - (n % 8);
    for (int i = 8; i < n8; i += 8) {
        #pragma unroll
        for (int k = 0; k < 8; ++k) r[k] = r[k] + sq_at(p, o + i + k, stride);
    }
    float res = ((r[0] + r[1]) + (r[2] + r[3])) + ((r[4] + r[5]) + (r[6] + r[7]));
    for (int i = n8; i < n; ++i) res = res + sq_at(p, o + i, stride);
    return res;
}

__device__ __forceinline__ float np_sumsq_row(const float* p, int stride) {
#pragma clang fp contract(off)
    const float p120 = np_block_sq(p, stride, 1,   120);
    const float p64  = np_block_sq(p, stride, 121, 64);
    const float p71  = np_block_sq(p, stride, 185, 71);
    const float s135 = p64 + p71;
    const float s255 = p120 + s135;
    return sq_at(p, 0, stride) + s255;
}

// bf16 round-to-nearest-even (same helper for A and B packs: consistency)
__device__ __forceinline__ unsigned short f32_to_bf16_rne(float f) {
    unsigned u = __float_as_uint(f);
    u += 0x7fffu + ((u >> 16) & 1u);
    return (unsigned short)(u >> 16);
}

// ---------------- prologue: xsq(128) | esq(4) | B-pack(1024 blocks) ---------
// B-pack layout [kc][t][lane][i] (slot->k map: k = kc*32 + (lane>>4)*8 + i,
// col c = t*16 + (lane&15)). A uses the SAME map -> any consistent bijection
// is correct regardless of the hardware's internal k ordering.
__global__ void vq_prologue_mfma(const float* __restrict__ x, const float* __restrict__ cb,
                                 float* __restrict__ xsq, float* __restrict__ esq,
                                 unsigned short* __restrict__ bh, unsigned short* __restrict__ bl) {
    const int bid = blockIdx.x;
    if (bid < 128) {                                   // xsq (np-exact)
        const int n = bid * 256 + threadIdx.x;
        const float* p = x + ((size_t)(n >> 10)) * (DIMS * 1024) + (n & 1023);
        xsq[n] = np_sumsq_row(p, 1024);
    } else if (bid < 132) {                            // esq (np-exact)
        const int c = (bid - 128) * 256 + threadIdx.x;
        esq[c] = np_sumsq_row(cb + (size_t)c * DIMS, 1);
    } else {                                           // two-level bf16 B pack
        const int idx = (bid - 132) * 256 + threadIdx.x;   // 0..262143
        const int i  = idx & 7;
        const int ln = (idx >> 3) & 63;
        const int t  = (idx >> 9) & 63;
        const int kc = idx >> 15;
        const int c  = t * 16 + (ln & 15);
        const int k  = kc * 32 + (ln >> 4) * 8 + i;
        const float v = cb[(size_t)c * DIMS + k];
        const unsigned short hbits = f32_to_bf16_rne(v);
        const float hv = __uint_as_float((unsigned)hbits << 16);
        bh[idx] = hbits;
        bl[idx] = f32_to_bf16_rne(v - hv);             // residual plane
    }
}

// ---------------- MFMA filter: approx v, top-3 codes per row ----------------
// Wave = 16 rows x all 1024 codes (64 col-tiles). Per tile: 8 kchunks x
// 2 MFMA (eh + el planes, separate acc chains). Epilogue per tile: per-lane
// top-2 insert (this lane's col). End: per-row 3-extraction lexmin merge over
// the 16-lane subgroup. C/D map (m89-verified): col=lane&15, row=(lane>>4)*4+j.
__global__ __launch_bounds__(256, 2)
void vq_mfma_filter(const float* __restrict__ x, const unsigned short* __restrict__ bh,
                    const unsigned short* __restrict__ bl, const float* __restrict__ esq,
                    int4* __restrict__ cand) {
    const int wid  = __builtin_amdgcn_readfirstlane((int)(threadIdx.x >> 6));
    const int lane = threadIdx.x & 63;
    const int rowblk = blockIdx.x * 4 + wid;       // 0..2047
    const int row0 = rowblk * 16;                  // 16 | 1024 -> one image
    const int b  = row0 >> 10;
    const int hw = (row0 & 1023) + (lane & 15);
    const float* xb = x + (size_t)b * (DIMS * 1024) + hw;
    const int g = lane >> 4;

    // A fragments: A[m = lane&15][k = kc*32 + g*8 + i], bf16 RNE on the fly
    bf16x8 afr[8];
    #pragma unroll
    for (int kc = 0; kc < 8; ++kc) {
        #pragma unroll
        for (int i = 0; i < 8; ++i) {
            const int k = kc * 32 + g * 8 + i;
            afr[kc][i] = (short)f32_to_bf16_rne(xb[(size_t)k * 1024]);
        }
    }

    float lv[4][2]; int lc[4][2];
    #pragma unroll
    for (int j = 0; j < 4; ++j) {
        lv[j][0] = 3.4e38f; lv[j][1] = 3.4e38f;
        lc[j][0] = 0x7fffffff; lc[j][1] = 0x7fffffff;
    }

    const bf16x8* bhv = reinterpret_cast<const bf16x8*>(bh);
    const bf16x8* blv = reinterpret_cast<const bf16x8*>(bl);

    for (int t = 0; t < 64; ++t) {
        f32x4 acch = {0.f, 0.f, 0.f, 0.f};
        f32x4 accl = {0.f, 0.f, 0.f, 0.f};
        #pragma unroll
        for (int kc = 0; kc < 8; ++kc) {
            const int bidx = (kc * 64 + t) * 64 + lane;    // coalesced dwordx4
            acch = __builtin_amdgcn_mfma_f32_16x16x32_bf16(afr[kc], bhv[bidx], acch, 0, 0, 0);
            accl = __builtin_amdgcn_mfma_f32_16x16x32_bf16(afr[kc], blv[bidx], accl, 0, 0, 0);
        }
        const int   c  = t * 16 + (lane & 15);
        const float es = esq[c];
        #pragma unroll
        for (int j = 0; j < 4; ++j) {
            // x_sq omitted: constant per row -> ordering-invariant for the filter
            const float v = fmaf(-2.0f, acch[j] + accl[j], es);
            if (v < lv[j][0]) { lv[j][1] = lv[j][0]; lc[j][1] = lc[j][0]; lv[j][0] = v; lc[j][0] = c; }
            else if (v < lv[j][1]) { lv[j][1] = v; lc[j][1] = c; }
        }
    }

    // per-row merge: 3 lexmin extractions over the 16-lane subgroup
    int c3[4][3];
    #pragma unroll
    for (int j = 0; j < 4; ++j) {
        float a1v = lv[j][0]; int a1c = lc[j][0];
        float a2v = lv[j][1]; int a2c = lc[j][1];
        #pragma unroll
        for (int e = 0; e < 3; ++e) {
            float mv = a1v; int mc = a1c;
            #pragma unroll
            for (int off = 1; off < 16; off <<= 1) {
                const float ov = __shfl_xor(mv, off, 16);
                const int   oc = __shfl_xor(mc, off, 16);
                if (ov < mv || (ov == mv && oc < mc)) { mv = ov; mc = oc; }
            }
            c3[j][e] = mc;
            if (a1c == mc) { a1v = a2v; a1c = a2c; a2v = 3.4e38f; a2c = 0x7fffffff; }  // pop owner
        }
    }
    if ((lane & 15) == 0) {
        #pragma unroll
        for (int j = 0; j < 4; ++j)
            cand[row0 + g * 4 + j] = make_int4(c3[j][0], c3[j][1], c3[j][2], 0);
    }
}

// ---------------- exact refine: np-order fp32 over 3 candidates/row ---------
__global__ __launch_bounds__(256, 2)
void vq_refine3(const float* __restrict__ x, const float* __restrict__ cb,
                const float* __restrict__ esq, const float* __restrict__ xsq,
                const int4* __restrict__ cand, int* __restrict__ out) {
    const int n  = blockIdx.x * 256 + threadIdx.x;
    const int b  = n >> 10;
    const int hw = n & 1023;
    const float* xr = x + (size_t)b * (DIMS * 1024) + hw;
    const int4 cd = cand[n];
    const int cc[3] = {cd.x, cd.y, cd.z};

    float acc[3] = {0.f, 0.f, 0.f};
    // exact dot: sequential fma, strictly ascending d (BLAS/np order)
    for (int d0 = 0; d0 < DIMS; d0 += 32) {
        float xv[32];
        #pragma unroll
        for (int i = 0; i < 32; ++i) xv[i] = xr[(size_t)(d0 + i) * 1024];
        #pragma unroll
        for (int k = 0; k < 3; ++k) {
            const float* ec = cb + (size_t)cc[k] * DIMS + d0;
            #pragma unroll
            for (int i = 0; i < 32; ++i) acc[k] = fmaf(xv[i], ec[i], acc[k]);
        }
    }
    {
#pragma clang fp contract(off)
        const float xs_n = xsq[n];
        float bestv = 3.4e38f; int bestc = 0x7fffffff;
        #pragma unroll
        for (int k = 0; k < 3; ++k) {
            const float t3 = xs_n - 2.0f * acc[k];
            const float v  = t3 + esq[cc[k]];
            if (v < bestv || (v == bestv && cc[k] < bestc)) { bestv = v; bestc = cc[k]; }
        }
        out[n] = bestc;
    }
}

// ===========================================================================
// fp32 fallback path — R12 verified (prologue + v7 main + reduce, 236us).
// Only used if ws_size < 1.7MB (never observed; kept for safety).
// ===========================================================================
__global__ void vq_prologue_f32(const float* __restrict__ x, const float* __restrict__ cb,
                                float* __restrict__ xsq, float* __restrict__ esq,
                                float4* __restrict__ et4) {
    const int bid = blockIdx.x;
    if (bid < 128) {
        const int n = bid * 256 + threadIdx.x;
        const float* p = x + ((size_t)(n >> 10)) * (DIMS * 1024) + (n & 1023);
        xsq[n] = np_sumsq_row(p, 1024);
    } else if (bid < 132) {
        const int c = (bid - 128) * 256 + threadIdx.x;
        esq[c] = np_sumsq_row(cb + (size_t)c * DIMS, 1);
    } else {
        const int idx = (bid - 132) * 256 + threadIdx.x;
        const int dk  = idx & 63;
        const int c   = idx >> 6;
        const float4 v = *reinterpret_cast<const float4*>(cb + (size_t)c * DIMS + dk * 4);
        et4[(size_t)dk * K_CODES + c] = v;
    }
}

__global__ __launch_bounds__(256, 2)
void vq_main7_kernel(const float* __restrict__ x, const float4* __restrict__ et4,
                     const float* __restrict__ esq, const float* __restrict__ xsq,
                     float2* __restrict__ cand) {
    const int wid  = __builtin_amdgcn_readfirstlane((int)(threadIdx.x >> 6));
    const int lane = threadIdx.x & 63;
    const int W     = blockIdx.x * 4 + wid;
    const int g     = W & 3;
    const int slice = W >> 2;
    const int c0    = g * 256 + lane;
    const int row_base = slice * 8;
    const int b    = row_base >> 10;
    const int hw0  = row_base & 1023;
    const float* xb = x + (size_t)b * (DIMS * 1024) + hw0;

    const float esq0 = esq[c0];
    const float esq1 = esq[c0 + 64];
    const float esq2 = esq[c0 + 128];
    const float esq3 = esq[c0 + 192];

    float acc0[8], acc1[8], acc2[8], acc3[8];
    #pragma unroll
    for (int r = 0; r < 8; ++r) { acc0[r] = 0.0f; acc1[r] = 0.0f; acc2[r] = 0.0f; acc3[r] = 0.0f; }

    for (int dk = 0; dk < DIMS / 4; ++dk) {
        const float4* ep = et4 + (size_t)dk * K_CODES;
        const float4 e0 = ep[c0];
        const float4 e1 = ep[c0 + 64];
        const float4 e2 = ep[c0 + 128];
        const float4 e3 = ep[c0 + 192];

        #pragma unroll
        for (int dd = 0; dd < 4; ++dd) {
            float xv[8];
            #pragma unroll
            for (int r = 0; r < 8; ++r)
                xv[r] = xb[(size_t)(dk * 4 + dd) * 1024 + r];
            const float ev0 = (dd == 0) ? e0.x : (dd == 1) ? e0.y : (dd == 2) ? e0.z : e0.w;
            const float ev1 = (dd == 0) ? e1.x : (dd == 1) ? e1.y : (dd == 2) ? e1.z : e1.w;
            const float ev2 = (dd == 0) ? e2.x : (dd == 1) ? e2.y : (dd == 2) ? e2.z : e2.w;
            const float ev3 = (dd == 0) ? e3.x : (dd == 1) ? e3.y : (dd == 2) ? e3.z : e3.w;
            #pragma unroll
            for (int r = 0; r < 8; ++r) acc0[r] = fmaf(xv[r], ev0, acc0[r]);
            #pragma unroll
            for (int r = 0; r < 8; ++r) acc1[r] = fmaf(xv[r], ev1, acc1[r]);
            #pragma unroll
            for (int r = 0; r < 8; ++r) acc2[r] = fmaf(xv[r], ev2, acc2[r]);
            #pragma unroll
            for (int r = 0; r < 8; ++r) acc3[r] = fmaf(xv[r], ev3, acc3[r]);
        }
    }

    {
#pragma clang fp contract(off)
        float keepv = 0.0f; int keepc = 0;
        #pragma unroll
        for (int r = 0; r < 8; ++r) {
            const float xs_r = xsq[row_base + r];
            const float v0 = (xs_r - 2.0f * acc0[r]) + esq0;
            const float v1 = (xs_r - 2.0f * acc1[r]) + esq1;
            const float v2 = (xs_r - 2.0f * acc2[r]) + esq2;
            const float v3 = (xs_r - 2.0f * acc3[r]) + esq3;
            float bv = v0; int bc = c0;
            if (v1 < bv) { bv = v1; bc = c0 + 64; }
            if (v2 < bv) { bv = v2; bc = c0 + 128; }
            if (v3 < bv) { bv = v3; bc = c0 + 192; }
            #pragma unroll
            for (int off = 1; off < 64; off <<= 1) {
                const float ov = __shfl_xor(bv, off, 64);
                const int   oc = __shfl_xor(bc, off, 64);
                if (ov < bv || (ov == bv && oc < bc)) { bv = ov; bc = oc; }
            }
            if (lane == r) { keepv = bv; keepc = bc; }
        }
        if (lane < 8) {
            cand[(size_t)g * NROWS + row_base + lane] =
                make_float2(keepv, __int_as_float(keepc));
        }
    }
}

__global__ void vq_reduce_kernel(const float2* __restrict__ cand, int* __restrict__ out) {
    const int row = blockIdx.x * 256 + threadIdx.x;
    float2 p = cand[row];
    float bv = p.x; int bc = __float_as_int(p.y);
    #pragma unroll
    for (int gg = 1; gg < 4; ++gg) {
        const float2 q = cand[(size_t)gg * NROWS + row];
        const float v = q.x; const int qc = __float_as_int(q.y);
        if (v < bv || (v == bv && qc < bc)) { bv = v; bc = qc; }
    }
    out[row] = bc;
}

// ===========================================================================
extern "C" void kernel_launch(void* const* d_in, const int* in_sizes, int n_in,
                              void* d_out, int out_size, void* d_ws, size_t ws_size,
                              hipStream_t stream) {
    const float* x  = (const float*)d_in[0];   // [32, 256, 32, 32]
    const float* cb = (const float*)d_in[1];   // [1024, 256]
    int* out = (int*)d_out;                    // [32768] int32
    float* ws = (float*)d_ws;

    if (ws_size >= WS_MFMA_NEED_BYTES) {
        unsigned short* bh = (unsigned short*)(ws + WS_BH);
        unsigned short* bl = (unsigned short*)(ws + WS_BL);
        float* esq = ws + WS_ESQ;
        float* xsq = ws + WS_XSQ;
        int4*  cnd = (int4*)(ws + WS_CAND);

        vq_prologue_mfma<<<128 + 4 + 1024, 256, 0, stream>>>(x, cb, xsq, esq, bh, bl);
        vq_mfma_filter<<<512, 256, 0, stream>>>(x, bh, bl, esq, cnd);
        vq_refine3<<<NROWS / 256, 256, 0, stream>>>(x, cb, esq, xsq, cnd, out);
        return;
    }
    // fp32 fallback (R12, verified 236us)
    {
        float4* et4  = (float4*)(ws + F32_ET);
        float*  esq  = ws + F32_ESQ;
        float*  xsq  = ws + F32_XSQ;
        float2* cand = (float2*)(ws + F32_CAND);

        vq_prologue_f32<<<128 + 4 + 256, 256, 0, stream>>>(x, cb, xsq, esq, et4);
        vq_main7_kernel<<<(NROWS / 8) * 4 / 4, 256, 0, stream>>>(x, et4, esq, xsq, cand);
        vq_reduce_kernel<<<NROWS / 256, 256, 0, stream>>>(cand, out);
    }
}

// Round 18
// 122.424 us; speedup vs baseline: 2.0349x; 1.7765x over previous
//
#include <hip/hip_runtime.h>

#define K_CODES 1024
#define DIMS    256
#define NROWS   32768   // B*H*W = 32*32*32

typedef __attribute__((ext_vector_type(8))) short bf16x8;
typedef __attribute__((ext_vector_type(4))) float f32x4;

// NOTE (R16 lesson): never gate host launch logic on __has_builtin of device
// builtins (host pass sees 0). mfma_f32_16x16x32_bf16 verified on gfx950.

// ---------------- MFMA-path ws layout (float units), ~1.05 MB ----------------
#define WS_BH    0                             // 262144 ushort = 131072 floats
#define WS_BL    (WS_BH + 131072)
#define WS_ESQ   (WS_BL + 131072)
#define WS_CAND  (WS_ESQ + K_CODES)            // int4 per row
#define WS_MFMA_NEED_FLOATS (WS_CAND + NROWS * 4)
#define WS_MFMA_NEED_BYTES  ((size_t)WS_MFMA_NEED_FLOATS * 4)

// fp32 fallback layout (R12 verified)
#define F32_ET    0
#define F32_ESQ   (F32_ET  + DIMS * K_CODES)
#define F32_XSQ   (F32_ESQ + K_CODES)
#define F32_CAND  (F32_XSQ + NROWS)
#define F32_NEED_FLOATS (F32_CAND + 4 * NROWS * 2)
#define F32_NEED_BYTES  ((size_t)F32_NEED_FLOATS * 4)

// ---------------------------------------------------------------------------
// numpy-bitwise sum of squares of a 256-element row (verified round 2).
// ---------------------------------------------------------------------------
__device__ __forceinline__ float sq_at(const float* p, int d, int stride) {
#pragma clang fp contract(off)
    const float v = p[(size_t)d * stride];
    return v * v;
}

__device__ __forceinline__ float np_block_sq(const float* p, int stride, int o, int n) {
#pragma clang fp contract(off)
    float r[8];
    #pragma unroll
    for (int k = 0; k < 8; ++k) r[k] = sq_at(p, o + k, stride);
    const int n8 = n - (n % 8);
    for (int i = 8; i < n8; i += 8) {
        #pragma unroll
        for (int k = 0; k < 8; ++k) r[k] = r[k] + sq_at(p, o + i + k, stride);
    }
    float res = ((r[0] + r[1]) + (r[2] + r[3])) + ((r[4] + r[5]) + (r[6] + r[7]));
    for (int i = n8; i < n; ++i) res = res + sq_at(p, o + i, stride);
    return res;
}

__device__ __forceinline__ float np_sumsq_row(const float* p, int stride) {
#pragma clang fp contract(off)
    const float p120 = np_block_sq(p, stride, 1,   120);
    const float p64  = np_block_sq(p, stride, 121, 64);
    const float p71  = np_block_sq(p, stride, 185, 71);
    const float s135 = p64 + p71;
    const float s255 = p120 + s135;
    return sq_at(p, 0, stride) + s255;
}

// bf16 round-to-nearest-even (same helper for A and B packs: consistency)
__device__ __forceinline__ unsigned short f32_to_bf16_rne(float f) {
    unsigned u = __float_as_uint(f);
    u += 0x7fffu + ((u >> 16) & 1u);
    return (unsigned short)(u >> 16);
}

// ---------------- prologue: esq(4 blocks) | B-pack(1024 blocks) -------------
// B-pack layout [kc][t][lane][i] (slot->k map: k = kc*32 + (lane>>4)*8 + i,
// col c = t*16 + (lane&15)). A uses the SAME map -> any consistent bijection
// is correct regardless of the hardware's internal k ordering.
__global__ void vq_prologue_mfma(const float* __restrict__ cb,
                                 float* __restrict__ esq,
                                 unsigned short* __restrict__ bh,
                                 unsigned short* __restrict__ bl) {
    const int bid = blockIdx.x;
    if (bid < 4) {                                     // esq (np-exact)
        const int c = bid * 256 + threadIdx.x;
        esq[c] = np_sumsq_row(cb + (size_t)c * DIMS, 1);
    } else {                                           // two-level bf16 B pack
        const int idx = (bid - 4) * 256 + threadIdx.x;     // 0..262143
        const int i  = idx & 7;
        const int ln = (idx >> 3) & 63;
        const int t  = (idx >> 9) & 63;
        const int kc = idx >> 15;
        const int c  = t * 16 + (ln & 15);
        const int k  = kc * 32 + (ln >> 4) * 8 + i;
        const float v = cb[(size_t)c * DIMS + k];
        const unsigned short hbits = f32_to_bf16_rne(v);
        const float hv = __uint_as_float((unsigned)hbits << 16);
        bh[idx] = hbits;
        bl[idx] = f32_to_bf16_rne(v - hv);             // residual plane
    }
}

// ---------------- MFMA filter (R17-verified core + LDS-staged B) ------------
// R17 post-mortem: every wave streamed the whole 1MB B from L2 (2GB total,
// ~13 TB/s effective -> 155us). Staging each 4-tile chunk in LDS shares it
// across the block's 4 waves: L2 traffic /4. Compute core byte-identical to
// the R17 PASSING kernel (A-frag map, mfma arg order, C/D map col=lane&15,
// row=(lane>>4)*4+j, per-lane top-2 + 3-extraction merge).
__global__ __launch_bounds__(256, 2)
void vq_mfma_filter(const float* __restrict__ x, const unsigned short* __restrict__ bh,
                    const unsigned short* __restrict__ bl, const float* __restrict__ esq,
                    int4* __restrict__ cand) {
    __shared__ int4 lbh[2048];     // 32 KB: chunk of 4 tiles, hi plane
    __shared__ int4 lbl[2048];     // 32 KB: lo plane

    const int tid  = (int)threadIdx.x;
    const int wid  = __builtin_amdgcn_readfirstlane(tid >> 6);
    const int lane = tid & 63;
    const int rowblk = blockIdx.x * 4 + wid;       // 0..2047
    const int row0 = rowblk * 16;                  // 16 | 1024 -> one image
    const int b  = row0 >> 10;
    const int hw = (row0 & 1023) + (lane & 15);
    const float* xb = x + (size_t)b * (DIMS * 1024) + hw;
    const int g = lane >> 4;

    // A fragments: A[m = lane&15][k = kc*32 + g*8 + i], bf16 RNE on the fly
    bf16x8 afr[8];
    #pragma unroll
    for (int kc = 0; kc < 8; ++kc) {
        #pragma unroll
        for (int i = 0; i < 8; ++i) {
            const int k = kc * 32 + g * 8 + i;
            afr[kc][i] = (short)f32_to_bf16_rne(xb[(size_t)k * 1024]);
        }
    }

    float lv[4][2]; int lc[4][2];
    #pragma unroll
    for (int j = 0; j < 4; ++j) {
        lv[j][0] = 3.4e38f; lv[j][1] = 3.4e38f;
        lc[j][0] = 0x7fffffff; lc[j][1] = 0x7fffffff;
    }

    const int4* bh4 = reinterpret_cast<const int4*>(bh);
    const int4* bl4 = reinterpret_cast<const int4*>(bl);

    for (int chunk = 0; chunk < 16; ++chunk) {
        __syncthreads();   // previous chunk's readers done
        // stage 4 tiles x 8 kc x 64 lanes x 16B per plane (coalesced, 16B/lane)
        #pragma unroll
        for (int e = 0; e < 8; ++e) {
            const int idx = e * 256 + tid;             // 0..2047
            const int ln_ = idx & 63;
            const int tt_ = (idx >> 6) & 3;
            const int kc_ = idx >> 8;
            const int gf  = (kc_ * 64 + chunk * 4 + tt_) * 64 + ln_;
            lbh[idx] = bh4[gf];
            lbl[idx] = bl4[gf];
        }
        __syncthreads();

        #pragma unroll
        for (int tt = 0; tt < 4; ++tt) {
            const int t = chunk * 4 + tt;
            f32x4 acch = {0.f, 0.f, 0.f, 0.f};
            f32x4 accl = {0.f, 0.f, 0.f, 0.f};
            #pragma unroll
            for (int kc = 0; kc < 8; ++kc) {
                const int li = (kc * 4 + tt) * 64 + lane;   // 16B/lane: 2-way free
                acch = __builtin_amdgcn_mfma_f32_16x16x32_bf16(
                    afr[kc], *reinterpret_cast<const bf16x8*>(&lbh[li]), acch, 0, 0, 0);
                accl = __builtin_amdgcn_mfma_f32_16x16x32_bf16(
                    afr[kc], *reinterpret_cast<const bf16x8*>(&lbl[li]), accl, 0, 0, 0);
            }
            const int   c  = t * 16 + (lane & 15);
            const float es = esq[c];
            #pragma unroll
            for (int j = 0; j < 4; ++j) {
                // x_sq omitted: constant per row -> ordering-invariant for filter
                const float v = fmaf(-2.0f, acch[j] + accl[j], es);
                if (v < lv[j][0]) { lv[j][1] = lv[j][0]; lc[j][1] = lc[j][0]; lv[j][0] = v; lc[j][0] = c; }
                else if (v < lv[j][1]) { lv[j][1] = v; lc[j][1] = c; }
            }
        }
    }

    // per-row merge: 3 lexmin extractions over the 16-lane subgroup
    int c3[4][3];
    #pragma unroll
    for (int j = 0; j < 4; ++j) {
        float a1v = lv[j][0]; int a1c = lc[j][0];
        float a2v = lv[j][1]; int a2c = lc[j][1];
        #pragma unroll
        for (int e = 0; e < 3; ++e) {
            float mv = a1v; int mc = a1c;
            #pragma unroll
            for (int off = 1; off < 16; off <<= 1) {
                const float ov = __shfl_xor(mv, off, 16);
                const int   oc = __shfl_xor(mc, off, 16);
                if (ov < mv || (ov == mv && oc < mc)) { mv = ov; mc = oc; }
            }
            c3[j][e] = mc;
            if (a1c == mc) { a1v = a2v; a1c = a2c; a2v = 3.4e38f; a2c = 0x7fffffff; }  // pop owner
        }
    }
    if ((lane & 15) == 0) {
        #pragma unroll
        for (int j = 0; j < 4; ++j)
            cand[row0 + g * 4 + j] = make_int4(c3[j][0], c3[j][1], c3[j][2], 0);
    }
}

// ---------------- exact refine: np-order fp32 over 3 candidates/row ---------
// xsq fused: np_sumsq_row inline (same verified function the xsq kernel used).
__global__ __launch_bounds__(256, 2)
void vq_refine3(const float* __restrict__ x, const float* __restrict__ cb,
                const float* __restrict__ esq, const int4* __restrict__ cand,
                int* __restrict__ out) {
    const int n  = blockIdx.x * 256 + threadIdx.x;
    const int b  = n >> 10;
    const int hw = n & 1023;
    const float* xr = x + (size_t)b * (DIMS * 1024) + hw;
    const int4 cd = cand[n];
    const int cc[3] = {cd.x, cd.y, cd.z};

    float acc[3] = {0.f, 0.f, 0.f};
    // exact dot: sequential fma, strictly ascending d (BLAS/np order)
    for (int d0 = 0; d0 < DIMS; d0 += 32) {
        float xv[32];
        #pragma unroll
        for (int i = 0; i < 32; ++i) xv[i] = xr[(size_t)(d0 + i) * 1024];
        #pragma unroll
        for (int k = 0; k < 3; ++k) {
            const float* ec = cb + (size_t)cc[k] * DIMS + d0;
            #pragma unroll
            for (int i = 0; i < 32; ++i) acc[k] = fmaf(xv[i], ec[i], acc[k]);
        }
    }
    const float xs_n = np_sumsq_row(xr, 1024);         // np-exact, fused
    {
#pragma clang fp contract(off)
        float bestv = 3.4e38f; int bestc = 0x7fffffff;
        #pragma unroll
        for (int k = 0; k < 3; ++k) {
            const float t3 = xs_n - 2.0f * acc[k];
            const float v  = t3 + esq[cc[k]];
            if (v < bestv || (v == bestv && cc[k] < bestc)) { bestv = v; bestc = cc[k]; }
        }
        out[n] = bestc;
    }
}

// ===========================================================================
// fp32 fallback path — R12 verified (prologue + v7 main + reduce, 236us).
// Only used if ws_size < 1.05MB (never observed; kept for safety).
// ===========================================================================
__global__ void vq_prologue_f32(const float* __restrict__ x, const float* __restrict__ cb,
                                float* __restrict__ xsq, float* __restrict__ esq,
                                float4* __restrict__ et4) {
    const int bid = blockIdx.x;
    if (bid < 128) {
        const int n = bid * 256 + threadIdx.x;
        const float* p = x + ((size_t)(n >> 10)) * (DIMS * 1024) + (n & 1023);
        xsq[n] = np_sumsq_row(p, 1024);
    } else if (bid < 132) {
        const int c = (bid - 128) * 256 + threadIdx.x;
        esq[c] = np_sumsq_row(cb + (size_t)c * DIMS, 1);
    } else {
        const int idx = (bid - 132) * 256 + threadIdx.x;
        const int dk  = idx & 63;
        const int c   = idx >> 6;
        const float4 v = *reinterpret_cast<const float4*>(cb + (size_t)c * DIMS + dk * 4);
        et4[(size_t)dk * K_CODES + c] = v;
    }
}

__global__ __launch_bounds__(256, 2)
void vq_main7_kernel(const float* __restrict__ x, const float4* __restrict__ et4,
                     const float* __restrict__ esq, const float* __restrict__ xsq,
                     float2* __restrict__ cand) {
    const int wid  = __builtin_amdgcn_readfirstlane((int)(threadIdx.x >> 6));
    const int lane = threadIdx.x & 63;
    const int W     = blockIdx.x * 4 + wid;
    const int g     = W & 3;
    const int slice = W >> 2;
    const int c0    = g * 256 + lane;
    const int row_base = slice * 8;
    const int b    = row_base >> 10;
    const int hw0  = row_base & 1023;
    const float* xb = x + (size_t)b * (DIMS * 1024) + hw0;

    const float esq0 = esq[c0];
    const float esq1 = esq[c0 + 64];
    const float esq2 = esq[c0 + 128];
    const float esq3 = esq[c0 + 192];

    float acc0[8], acc1[8], acc2[8], acc3[8];
    #pragma unroll
    for (int r = 0; r < 8; ++r) { acc0[r] = 0.0f; acc1[r] = 0.0f; acc2[r] = 0.0f; acc3[r] = 0.0f; }

    for (int dk = 0; dk < DIMS / 4; ++dk) {
        const float4* ep = et4 + (size_t)dk * K_CODES;
        const float4 e0 = ep[c0];
        const float4 e1 = ep[c0 + 64];
        const float4 e2 = ep[c0 + 128];
        const float4 e3 = ep[c0 + 192];

        #pragma unroll
        for (int dd = 0; dd < 4; ++dd) {
            float xv[8];
            #pragma unroll
            for (int r = 0; r < 8; ++r)
                xv[r] = xb[(size_t)(dk * 4 + dd) * 1024 + r];
            const float ev0 = (dd == 0) ? e0.x : (dd == 1) ? e0.y : (dd == 2) ? e0.z : e0.w;
            const float ev1 = (dd == 0) ? e1.x : (dd == 1) ? e1.y : (dd == 2) ? e1.z : e1.w;
            const float ev2 = (dd == 0) ? e2.x : (dd == 1) ? e2.y : (dd == 2) ? e2.z : e2.w;
            const float ev3 = (dd == 0) ? e3.x : (dd == 1) ? e3.y : (dd == 2) ? e3.z : e3.w;
            #pragma unroll
            for (int r = 0; r < 8; ++r) acc0[r] = fmaf(xv[r], ev0, acc0[r]);
            #pragma unroll
            for (int r = 0; r < 8; ++r) acc1[r] = fmaf(xv[r], ev1, acc1[r]);
            #pragma unroll
            for (int r = 0; r < 8; ++r) acc2[r] = fmaf(xv[r], ev2, acc2[r]);
            #pragma unroll
            for (int r = 0; r < 8; ++r) acc3[r] = fmaf(xv[r], ev3, acc3[r]);
        }
    }

    {
#pragma clang fp contract(off)
        float keepv = 0.0f; int keepc = 0;
        #pragma unroll
        for (int r = 0; r < 8; ++r) {
            const float xs_r = xsq[row_base + r];
            const float v0 = (xs_r - 2.0f * acc0[r]) + esq0;
            const float v1 = (xs_r - 2.0f * acc1[r]) + esq1;
            const float v2 = (xs_r - 2.0f * acc2[r]) + esq2;
            const float v3 = (xs_r - 2.0f * acc3[r]) + esq3;
            float bv = v0; int bc = c0;
            if (v1 < bv) { bv = v1; bc = c0 + 64; }
            if (v2 < bv) { bv = v2; bc = c0 + 128; }
            if (v3 < bv) { bv = v3; bc = c0 + 192; }
            #pragma unroll
            for (int off = 1; off < 64; off <<= 1) {
                const float ov = __shfl_xor(bv, off, 64);
                const int   oc = __shfl_xor(bc, off, 64);
                if (ov < bv || (ov == bv && oc < bc)) { bv = ov; bc = oc; }
            }
            if (lane == r) { keepv = bv; keepc = bc; }
        }
        if (lane < 8) {
            cand[(size_t)g * NROWS + row_base + lane] =
                make_float2(keepv, __int_as_float(keepc));
        }
    }
}

__global__ void vq_reduce_kernel(const float2* __restrict__ cand, int* __restrict__ out) {
    const int row = blockIdx.x * 256 + threadIdx.x;
    float2 p = cand[row];
    float bv = p.x; int bc = __float_as_int(p.y);
    #pragma unroll
    for (int gg = 1; gg < 4; ++gg) {
        const float2 q = cand[(size_t)gg * NROWS + row];
        const float v = q.x; const int qc = __float_as_int(q.y);
        if (v < bv || (v == bv && qc < bc)) { bv = v; bc = qc; }
    }
    out[row] = bc;
}

// ===========================================================================
extern "C" void kernel_launch(void* const* d_in, const int* in_sizes, int n_in,
                              void* d_out, int out_size, void* d_ws, size_t ws_size,
                              hipStream_t stream) {
    const float* x  = (const float*)d_in[0];   // [32, 256, 32, 32]
    const float* cb = (const float*)d_in[1];   // [1024, 256]
    int* out = (int*)d_out;                    // [32768] int32
    float* ws = (float*)d_ws;

    if (ws_size >= WS_MFMA_NEED_BYTES) {
        unsigned short* bh = (unsigned short*)(ws + WS_BH);
        unsigned short* bl = (unsigned short*)(ws + WS_BL);
        float* esq = ws + WS_ESQ;
        int4*  cnd = (int4*)(ws + WS_CAND);

        vq_prologue_mfma<<<4 + 1024, 256, 0, stream>>>(cb, esq, bh, bl);
        vq_mfma_filter<<<512, 256, 0, stream>>>(x, bh, bl, esq, cnd);
        vq_refine3<<<NROWS / 256, 256, 0, stream>>>(x, cb, esq, cnd, out);
        return;
    }
    // fp32 fallback (R12, verified 236us)
    {
        float4* et4  = (float4*)(ws + F32_ET);
        float*  esq  = ws + F32_ESQ;
        float*  xsq  = ws + F32_XSQ;
        float2* cand = (float2*)(ws + F32_CAND);

        vq_prologue_f32<<<128 + 4 + 256, 256, 0, stream>>>(x, cb, xsq, esq, et4);
        vq_main7_kernel<<<(NROWS / 8) * 4 / 4, 256, 0, stream>>>(x, et4, esq, xsq, cand);
        vq_reduce_kernel<<<NROWS / 256, 256, 0, stream>>>(cand, out);
    }
}